// Round 7
// baseline (12570.553 us; speedup 1.0000x reference)
//
#include <hip/hip_runtime.h>
#include <hip/hip_bf16.h>

typedef short s16x8 __attribute__((ext_vector_type(8)));
typedef short s16x4 __attribute__((ext_vector_type(4)));
typedef int   i32x4 __attribute__((ext_vector_type(4)));
typedef float f32x4 __attribute__((ext_vector_type(4)));
typedef float f32x2 __attribute__((ext_vector_type(2)));

#define T_STEPS 1024
#define BATCH   128
#define DIN     256
#define DH      256

static __device__ __forceinline__ short f2bf(float f){ return __builtin_bit_cast(short,(__bf16)f); }
static __device__ __forceinline__ float sigf(float x){ return 1.f/(1.f+__expf(-x)); }
static __device__ __forceinline__ float tanhfast(float x){ return 1.f-2.f/(1.f+__expf(2.f*x)); }

// ===================== FAST PATH (CU-local, sync-free) =====================
// Prepass: W -> bf16 MFMA-B-fragment layout in d_ws (1 MiB).
// frag index F = w*128 + b*64 + gate*16 + kk ; portion p = F*64 + lane.
// elem s: k = kk*32 + (lane>>4)*8 + s ; col = w*32 + b*16 + (lane&15).
__global__ void build_frags(const float* __restrict__ Wf, const float* __restrict__ Wi,
                            const float* __restrict__ Wg, const float* __restrict__ Wo,
                            unsigned short* __restrict__ frag) {
  const float* Wm[4] = {Wf, Wi, Wg, Wo};
  int p0 = blockIdx.x * 256 + threadIdx.x;      // 64 blocks x 256 thr = 16384
#pragma unroll
  for (int i = 0; i < 4; ++i) {
    int p = p0 + i * 16384;                     // 65536 portions
    int lane = p & 63;
    int F = p >> 6;
    int kk = F & 15, gate = (F >> 4) & 3, b = (F >> 6) & 1, w = F >> 7;
    int k0 = kk * 32 + (lane >> 4) * 8;
    int col = w * 32 + b * 16 + (lane & 15);
    const float* src = Wm[gate] + (size_t)k0 * DH + col;
    unsigned short* dst = frag + (size_t)p * 8;
#pragma unroll
    for (int s = 0; s < 8; ++s) dst[s] = (unsigned short)f2bf(src[(size_t)s * DH]);
  }
}

#define LDF(dst, base, OFF) \
  asm volatile("global_load_dwordx4 %0, %1, off offset:" #OFF : "=v"(dst) : "v"(base) : "memory")
#define WAITV(N) do { asm volatile("s_waitcnt vmcnt(" #N ")" ::: "memory"); \
  __builtin_amdgcn_sched_barrier(0); } while (0)

#define HALF_ISSUE(B) do { \
  LDF(bq[B][0], fwp, 0); LDF(bq[B][1], fwp, 1024); \
  LDF(bq[B][2], fwp, 2048); LDF(bq[B][3], fwp, 3072); \
  LDF(bq[B][4], fwp2, 0); LDF(bq[B][5], fwp2, 1024); \
  LDF(bq[B][6], fwp2, 2048); LDF(bq[B][7], fwp2, 3072); \
  fwp += 8192; fwp2 += 8192; } while (0)

#define HALF_MFMA(B, AARR, BI, GI) do { \
  acc[BI][GI] = __builtin_amdgcn_mfma_f32_16x16x32_bf16(AARR[0], __builtin_bit_cast(s16x8, bq[B][0]), acc[BI][GI], 0,0,0); \
  acc[BI][GI] = __builtin_amdgcn_mfma_f32_16x16x32_bf16(AARR[1], __builtin_bit_cast(s16x8, bq[B][1]), acc[BI][GI], 0,0,0); \
  acc[BI][GI] = __builtin_amdgcn_mfma_f32_16x16x32_bf16(AARR[2], __builtin_bit_cast(s16x8, bq[B][2]), acc[BI][GI], 0,0,0); \
  acc[BI][GI] = __builtin_amdgcn_mfma_f32_16x16x32_bf16(AARR[3], __builtin_bit_cast(s16x8, bq[B][3]), acc[BI][GI], 0,0,0); \
  acc[BI][GI] = __builtin_amdgcn_mfma_f32_16x16x32_bf16(AARR[4], __builtin_bit_cast(s16x8, bq[B][4]), acc[BI][GI], 0,0,0); \
  acc[BI][GI] = __builtin_amdgcn_mfma_f32_16x16x32_bf16(AARR[5], __builtin_bit_cast(s16x8, bq[B][5]), acc[BI][GI], 0,0,0); \
  acc[BI][GI] = __builtin_amdgcn_mfma_f32_16x16x32_bf16(AARR[6], __builtin_bit_cast(s16x8, bq[B][6]), acc[BI][GI], 0,0,0); \
  acc[BI][GI] = __builtin_amdgcn_mfma_f32_16x16x32_bf16(AARR[7], __builtin_bit_cast(s16x8, bq[B][7]), acc[BI][GI], 0,0,0); } while (0)

#define EPI(BI, CBX) do { \
  _Pragma("unroll") \
  for (int r = 0; r < 4; ++r) { \
    float zf = acc[BI][0][r] + bia[0][BI]; \
    float zi = acc[BI][1][r] + bia[1][BI]; \
    float zg = acc[BI][2][r] + bia[2][BI]; \
    float zo = acc[BI][3][r] + bia[3][BI]; \
    float cn = sigf(zf) * cs[BI][r] + sigf(zi) * tanhfast(zg); \
    cs[BI][r] = cn; \
    float hv = sigf(zo) * tanhfast(cn); \
    hq[BI][r] = hv; \
    if (grp < 2) HL[pw * 4352 + (grp * 4 + r) * 272 + (CBX)] = (unsigned short)f2bf(hv); \
  } } while (0)

__global__ __launch_bounds__(512, 2)
void lstm_cu(const float* __restrict__ X,
             const float* __restrict__ bfv, const float* __restrict__ biv,
             const float* __restrict__ bgv, const float* __restrict__ bov,
             const unsigned short* __restrict__ frag,
             float* __restrict__ out)
{
  const int tid = threadIdx.x;
  const int lane = tid & 63, w = tid >> 6;      // 8 waves; wave owns h-cols [32w,32w+32)
  const int grp = lane >> 4, l15 = lane & 15;
  const int g8 = blockIdx.x * 8;                // batch rows [g8, g8+8)

  // A-fragment LDS, double-buffered, 272-elem rows (16B-aligned, even bank spread)
  __shared__ unsigned short XL[2 * 16 * 272];   // x(t) bf16, rows 8..15 stay zero
  __shared__ unsigned short HL[2 * 16 * 272];   // h(t) bf16, rows 8..15 stay zero

  for (int i = tid; i < 2 * 16 * 272; i += 512) { XL[i] = 0; HL[i] = 0; }

  const int cb0 = w * 32 + l15, cb1 = w * 32 + 16 + l15;
  float bia[4][2];
  {
    const float* Bv[4] = {bfv, biv, bgv, bov};
#pragma unroll
    for (int g = 0; g < 4; ++g) { bia[g][0] = Bv[g][cb0]; bia[g][1] = Bv[g][cb1]; }
  }

  // x staging role: thread -> (row = tid>>6, 4-col chunk = (tid&63)*4)
  const int xr = tid >> 6, xc = (tid & 63) * 4;

  // stage x(0) into XL[0]
  {
    f32x4 v = *(const f32x4*)(X + ((size_t)0 * BATCH + g8 + xr) * DIN + xc);
    s16x4 h4; h4[0]=f2bf(v[0]); h4[1]=f2bf(v[1]); h4[2]=f2bf(v[2]); h4[3]=f2bf(v[3]);
    *(s16x4*)&XL[0 * 4352 + xr * 272 + xc] = h4;
  }
  __syncthreads();

  // prefetch x(1) (issue-only asm; drained at step top)
  i32x4 xq;
  LDF(xq, (const char*)(X + ((size_t)1 * BATCH + g8 + xr) * DIN + xc), 0);

  const char* fragw = (const char*)frag + (size_t)w * 131072;
  float cs[2][4] = {{0,0,0,0},{0,0,0,0}};
  float hq[2][4] = {{0,0,0,0},{0,0,0,0}};

  for (int t = 0; t < T_STEPS; ++t) {
    const int pr = t & 1, pw = pr ^ 1;

    // drain xq (and last step's out-stores, long since landed)
    asm volatile("s_waitcnt vmcnt(0)" ::: "memory");
    __builtin_amdgcn_sched_barrier(0);

    // stage x(t+1) -> XL[pw]
    {
      f32x4 v = __builtin_bit_cast(f32x4, xq);
      s16x4 h4; h4[0]=f2bf(v[0]); h4[1]=f2bf(v[1]); h4[2]=f2bf(v[2]); h4[3]=f2bf(v[3]);
      *(s16x4*)&XL[pw * 4352 + xr * 272 + xc] = h4;
    }

    // A-fragments (compiler ds_read_b128 + tracked lgkm waits)
    s16x8 ax[8], ah[8];
#pragma unroll
    for (int q = 0; q < 8; ++q) {
      ax[q] = *(const s16x8*)&XL[pr * 4352 + l15 * 272 + q * 32 + grp * 8];
      ah[q] = *(const s16x8*)&HL[pr * 4352 + l15 * 272 + q * 32 + grp * 8];
    }

    f32x4 acc[2][4];
#pragma unroll
    for (int b = 0; b < 2; ++b)
#pragma unroll
      for (int g = 0; g < 4; ++g) acc[b][g] = (f32x4){0.f,0.f,0.f,0.f};

    // B-fragment stream: 16 half-tiles, ring-3, counted vmcnt
    i32x4 bq[3][8];
    const char* fwp  = fragw + lane * 16;
    const char* fwp2 = fwp + 4096;

    HALF_ISSUE(0); HALF_ISSUE(1);
    HALF_ISSUE(2); WAITV(16); HALF_MFMA(0, ax, 0, 0);   // m=0
    HALF_ISSUE(0); WAITV(16); HALF_MFMA(1, ah, 0, 0);   // m=1
    HALF_ISSUE(1); WAITV(16); HALF_MFMA(2, ax, 0, 1);   // m=2
    HALF_ISSUE(2); WAITV(16); HALF_MFMA(0, ah, 0, 1);   // m=3
    HALF_ISSUE(0); WAITV(16); HALF_MFMA(1, ax, 0, 2);   // m=4
    HALF_ISSUE(1); WAITV(16); HALF_MFMA(2, ah, 0, 2);   // m=5
    HALF_ISSUE(2); WAITV(16); HALF_MFMA(0, ax, 0, 3);   // m=6
    HALF_ISSUE(0); WAITV(16); HALF_MFMA(1, ah, 0, 3);   // m=7
    EPI(0, cb0);                                        // overlaps halves 8,9 in flight
    HALF_ISSUE(1); WAITV(16); HALF_MFMA(2, ax, 1, 0);   // m=8
    HALF_ISSUE(2); WAITV(16); HALF_MFMA(0, ah, 1, 0);   // m=9
    HALF_ISSUE(0); WAITV(16); HALF_MFMA(1, ax, 1, 1);   // m=10
    HALF_ISSUE(1); WAITV(16); HALF_MFMA(2, ah, 1, 1);   // m=11
    HALF_ISSUE(2); WAITV(16); HALF_MFMA(0, ax, 1, 2);   // m=12
    HALF_ISSUE(0); WAITV(16); HALF_MFMA(1, ah, 1, 2);   // m=13
    WAITV(8);  HALF_MFMA(2, ax, 1, 3);                  // m=14
    WAITV(0);  HALF_MFMA(0, ah, 1, 3);                  // m=15

    // prefetch x(t+2) (issue-only; ages across epilogue+barrier)
    {
      const int tp = (t + 2 < T_STEPS) ? t + 2 : T_STEPS - 1;
      LDF(xq, (const char*)(X + ((size_t)tp * BATCH + g8 + xr) * DIN + xc), 0);
    }

    EPI(1, cb1);

    // out stores (plain; drained at next step top)
    if (grp < 2) {
      size_t rb = ((size_t)t * BATCH + g8 + grp * 4) * DH;
#pragma unroll
      for (int r = 0; r < 4; ++r) {
        out[rb + (size_t)r * DH + cb0] = hq[0][r];
        out[rb + (size_t)r * DH + cb1] = hq[1][r];
      }
    }

    // one intra-CU barrier per step (ds drained; VMEM stays in flight)
    asm volatile("s_waitcnt lgkmcnt(0)" ::: "memory");
    __builtin_amdgcn_sched_barrier(0);
    __builtin_amdgcn_s_barrier();
    __builtin_amdgcn_sched_barrier(0);
  }

  // final hx, cx from registers (WG owns its rows entirely)
  if (grp < 2) {
    const size_t base = (size_t)T_STEPS * BATCH * DH;
#pragma unroll
    for (int r = 0; r < 4; ++r) {
      size_t idx = (size_t)(g8 + grp * 4 + r) * DH;
      out[base + idx + cb0] = hq[0][r];
      out[base + idx + cb1] = hq[1][r];
      out[base + BATCH * DH + idx + cb0] = cs[0][r];
      out[base + BATCH * DH + idx + cb1] = cs[1][r];
    }
  }
}

// ===================== FALLBACK (round-3, proven) =====================
static __device__ __forceinline__ i32x4 ld16_cc(const void* p){
  i32x4 r; asm volatile("global_load_dwordx4 %0, %1, off sc0 sc1" : "=v"(r) : "v"(p) : "memory"); return r;
}
static __device__ __forceinline__ unsigned ld4_cc(const void* p){
  unsigned r; asm volatile("global_load_dword %0, %1, off sc0 sc1\ns_waitcnt vmcnt(0)" : "=v"(r) : "v"(p) : "memory"); return r;
}
static __device__ __forceinline__ void st4_cc(void* p, unsigned v){
  asm volatile("global_store_dword %0, %1, off sc0 sc1" :: "v"(p), "v"(v) : "memory");
}
static __device__ __forceinline__ s16x8 cvt8(f32x4 a, f32x4 b){
  s16x8 r;
  r[0]=f2bf(a[0]); r[1]=f2bf(a[1]); r[2]=f2bf(a[2]); r[3]=f2bf(a[3]);
  r[4]=f2bf(b[0]); r[5]=f2bf(b[1]); r[6]=f2bf(b[2]); r[7]=f2bf(b[3]);
  return r;
}

__global__ __launch_bounds__(256, 1)
void lstm_rc_fb(const float* __restrict__ X,
                const float* __restrict__ Wf, const float* __restrict__ bfv,
                const float* __restrict__ Wi, const float* __restrict__ biv,
                const float* __restrict__ Wg, const float* __restrict__ bgv,
                const float* __restrict__ Wo, const float* __restrict__ bov,
                float* __restrict__ out,
                unsigned short* __restrict__ hbuf,
                unsigned int* __restrict__ flags,
                int needEnd)
{
  const int bid = blockIdx.x;
  const int r   = bid & 7;
  const int csl = bid >> 3;
  const int tid = threadIdx.x;
  const int lane = tid & 63, wv = tid >> 6;
  const int grp = lane >> 4, l15 = lane & 15;
  const int r0 = r * 16;

  __shared__ short bfx[64 * 64 * 8];
  __shared__ float elds[4 * 16 * 36];

  s16x8 bh[2][8];
  {
    const float* Wm[4] = {Wf, Wi, Wg, Wo};
    const int gate = l15 >> 2, jj = l15 & 3;
    const float* Wsrc = Wm[gate];
#pragma unroll
    for (int n2 = 0; n2 < 2; ++n2) {
      const int hc = csl * 32 + (wv * 2 + n2) * 4 + jj;
#pragma unroll
      for (int kk = 0; kk < 16; ++kk) {
        const float* p = Wsrc + (size_t)(kk * 32 + grp * 8) * DH + hc;
        s16x8 f;
#pragma unroll
        for (int s = 0; s < 8; ++s) f[s] = f2bf(p[(size_t)s * DH]);
        if (kk < 8) *(s16x8*)&bfx[(((wv * 2 + n2) * 8 + kk) * 64 + lane) * 8] = f;
        else        bh[n2][kk - 8] = f;
      }
    }
  }

  const int colg = csl * 32 + wv * 8 + 2 * grp;
  float bia[4][2];
  {
    const float* Bv[4] = {bfv, biv, bgv, bov};
#pragma unroll
    for (int g = 0; g < 4; ++g) { bia[g][0] = Bv[g][colg]; bia[g][1] = Bv[g][colg + 1]; }
  }
  __syncthreads();

  f32x4 xr[16];
  {
    const float* xs0 = X + (size_t)(r0 + l15) * DIN + grp * 8;
#pragma unroll
    for (int kk = 0; kk < 8; ++kk) {
      xr[2 * kk]     = *(const f32x4*)(xs0 + kk * 32);
      xr[2 * kk + 1] = *(const f32x4*)(xs0 + kk * 32 + 4);
    }
  }
  f32x4 accx0 = {0.f,0.f,0.f,0.f}, accx1 = {0.f,0.f,0.f,0.f};
#pragma unroll
  for (int kk = 0; kk < 8; ++kk) {
    s16x8 fa = cvt8(xr[2 * kk], xr[2 * kk + 1]);
    s16x8 b0 = *(const s16x8*)&bfx[(((wv * 2 + 0) * 8 + kk) * 64 + lane) * 8];
    s16x8 b1 = *(const s16x8*)&bfx[(((wv * 2 + 1) * 8 + kk) * 64 + lane) * 8];
    accx0 = __builtin_amdgcn_mfma_f32_16x16x32_bf16(fa, b0, accx0, 0, 0, 0);
    accx1 = __builtin_amdgcn_mfma_f32_16x16x32_bf16(fa, b1, accx1, 0, 0, 0);
  }

  unsigned* myflag = flags + (r * 32 + csl);
  const unsigned* pollp = flags + (r * 32 + (lane & 7));
  float* eldsw = &elds[wv * 16 * 36];
  float cs0 = 0.f, cs1 = 0.f, h0s = 0.f, h1s = 0.f;

  for (int t = 0; t < T_STEPS; ++t) {
    while (1) {
      unsigned v = ld4_cc(pollp);
      if (__all((int)(v >= (unsigned)t))) break;
    }
    __builtin_amdgcn_sched_barrier(0);

    const unsigned short* hr = hbuf + (size_t)(t & 1) * (BATCH * DH)
                             + (size_t)(r0 + l15) * DH + grp * 8;
    i32x4 hraw[8];
#pragma unroll
    for (int q = 0; q < 8; ++q) hraw[q] = ld16_cc(hr + q * 32);
    asm volatile("s_waitcnt vmcnt(0)" ::: "memory");
    __builtin_amdgcn_sched_barrier(0);

    f32x4 acc0 = accx0, acc1 = accx1;
#pragma unroll
    for (int q = 0; q < 8; ++q) {
      s16x8 ah = __builtin_bit_cast(s16x8, hraw[q]);
      acc0 = __builtin_amdgcn_mfma_f32_16x16x32_bf16(ah, bh[0][q], acc0, 0, 0, 0);
      acc1 = __builtin_amdgcn_mfma_f32_16x16x32_bf16(ah, bh[1][q], acc1, 0, 0, 0);
    }

#pragma unroll
    for (int rr = 0; rr < 4; ++rr) {
      eldsw[(grp * 4 + rr) * 36 + l15]      = acc0[rr];
      eldsw[(grp * 4 + rr) * 36 + 16 + l15] = acc1[rr];
    }
    asm volatile("s_waitcnt lgkmcnt(0)" ::: "memory");
    __builtin_amdgcn_sched_barrier(0);
    float z0[4], z1[4];
    const int hc0 = 2 * grp, hc1 = 2 * grp + 1;
#pragma unroll
    for (int g = 0; g < 4; ++g) {
      z0[g] = eldsw[l15 * 36 + ((hc0 >> 2) << 4) + 4 * g + (hc0 & 3)];
      z1[g] = eldsw[l15 * 36 + ((hc1 >> 2) << 4) + 4 * g + (hc1 & 3)];
    }
    {
      float zf = z0[0] + bia[0][0], zi = z0[1] + bia[1][0];
      float zg = z0[2] + bia[2][0], zo = z0[3] + bia[3][0];
      cs0 = sigf(zf) * cs0 + sigf(zi) * tanhfast(zg);
      h0s = sigf(zo) * tanhfast(cs0);
    }
    {
      float zf = z1[0] + bia[0][1], zi = z1[1] + bia[1][1];
      float zg = z1[2] + bia[2][1], zo = z1[3] + bia[3][1];
      cs1 = sigf(zf) * cs1 + sigf(zi) * tanhfast(zg);
      h1s = sigf(zo) * tanhfast(cs1);
    }
    const int row = r0 + l15;
    {
      unsigned hpk = (unsigned)(unsigned short)f2bf(h0s)
                   | ((unsigned)(unsigned short)f2bf(h1s) << 16);
      st4_cc(hbuf + (size_t)((t + 1) & 1) * (BATCH * DH)
             + (size_t)row * DH + colg, hpk);
    }
    asm volatile("s_waitcnt vmcnt(0)" ::: "memory");
    __syncthreads();
    if (tid == 0) st4_cc(myflag, (unsigned)(t + 1));

    {
      f32x2 ov; ov[0] = h0s; ov[1] = h1s;
      *(f32x2*)(out + ((size_t)t * BATCH + row) * DH + colg) = ov;
    }
    {
      const int tnx = (t + 1 < T_STEPS) ? t + 1 : T_STEPS - 1;
      const float* xs = X + ((size_t)tnx * BATCH + r0 + l15) * DIN + grp * 8;
#pragma unroll
      for (int kk = 0; kk < 8; ++kk) {
        xr[2 * kk]     = *(const f32x4*)(xs + kk * 32);
        xr[2 * kk + 1] = *(const f32x4*)(xs + kk * 32 + 4);
      }
    }
    accx0 = (f32x4){0.f,0.f,0.f,0.f}; accx1 = (f32x4){0.f,0.f,0.f,0.f};
#pragma unroll
    for (int kk = 0; kk < 8; ++kk) {
      s16x8 fa = cvt8(xr[2 * kk], xr[2 * kk + 1]);
      s16x8 b0 = *(const s16x8*)&bfx[(((wv * 2 + 0) * 8 + kk) * 64 + lane) * 8];
      s16x8 b1 = *(const s16x8*)&bfx[(((wv * 2 + 1) * 8 + kk) * 64 + lane) * 8];
      accx0 = __builtin_amdgcn_mfma_f32_16x16x32_bf16(fa, b0, accx0, 0, 0, 0);
      accx1 = __builtin_amdgcn_mfma_f32_16x16x32_bf16(fa, b1, accx1, 0, 0, 0);
    }
  }

  if (needEnd) {
    if (wv == 0) {
      const unsigned* fp = flags + ((lane >> 3) * 32 + (lane & 7));
      while (ld4_cc(fp) < (unsigned)T_STEPS) __builtin_amdgcn_s_sleep(1);
    }
    __syncthreads();
  }
  {
    const size_t base = (size_t)T_STEPS * BATCH * DH;
    const size_t idx  = (size_t)(r0 + l15) * DH + colg;
    out[base + idx]     = h0s;
    out[base + idx + 1] = h1s;
    out[base + BATCH * DH + idx]     = cs0;
    out[base + BATCH * DH + idx + 1] = cs1;
  }
}

extern "C" void kernel_launch(void* const* d_in, const int* in_sizes, int n_in,
                              void* d_out, int out_size, void* d_ws, size_t ws_size,
                              hipStream_t stream) {
  const float* X   = (const float*)d_in[0];
  const float* Wf  = (const float*)d_in[1];
  const float* bf_ = (const float*)d_in[2];
  const float* Wi  = (const float*)d_in[3];
  const float* bi_ = (const float*)d_in[4];
  const float* Wg  = (const float*)d_in[5];
  const float* bg_ = (const float*)d_in[6];
  const float* Wo  = (const float*)d_in[7];
  const float* bo_ = (const float*)d_in[8];
  float* out = (float*)d_out;

  if (ws_size >= (size_t)(1u << 20)) {
    // FAST: prepass builds fragment buffer, main kernel is CU-local
    unsigned short* frag = (unsigned short*)d_ws;
    build_frags<<<64, 256, 0, stream>>>(Wf, Wi, Wg, Wo, frag);
    lstm_cu<<<16, 512, 0, stream>>>(X, bf_, bi_, bg_, bo_, frag, out);
    return;
  }

  // FALLBACK: round-3 proven path
  const size_t hbytes = (size_t)2 * BATCH * DH * 2;
  const size_t fbytes = 2048;
  unsigned short* hbuf;
  unsigned int*   flags;
  int needEnd;
  if (ws_size >= hbytes + fbytes) {
    hbuf  = (unsigned short*)d_ws;
    flags = (unsigned int*)((unsigned char*)d_ws + hbytes);
    needEnd = 0;
    hipMemsetAsync(d_ws, 0, hbytes + fbytes, stream);
  } else {
    unsigned char* tail = (unsigned char*)d_out + (size_t)T_STEPS * BATCH * DH * 4;
    hbuf  = (unsigned short*)tail;
    flags = (unsigned int*)(tail + hbytes);
    needEnd = 1;
    hipMemsetAsync(tail, 0, hbytes + fbytes, stream);
  }
  lstm_rc_fb<<<64, 256, 0, stream>>>(X, Wf, bf_, Wi, bi_, Wg, bg_,
                                     Wo, bo_, out, hbuf, flags, needEnd);
}

// Round 8
// 4923.079 us; speedup vs baseline: 2.5534x; 2.5534x over previous
//
#include <hip/hip_runtime.h>
#include <hip/hip_bf16.h>

typedef short s16x8 __attribute__((ext_vector_type(8)));
typedef int   i32x4 __attribute__((ext_vector_type(4)));
typedef unsigned u32x2 __attribute__((ext_vector_type(2)));
typedef float f32x4 __attribute__((ext_vector_type(4)));
typedef float f32x2 __attribute__((ext_vector_type(2)));

#define T_STEPS 1024
#define BATCH   128
#define DIN     256
#define DH      256
#define NWG     64     // 8 batch-groups (x16 rows) x 8 column-slices (x32 h-cols)
#define NTHREADS 256

static __device__ __forceinline__ short f2bf(float f){ return __builtin_bit_cast(short,(__bf16)f); }
static __device__ __forceinline__ float sigf(float x){ return 1.f/(1.f+__expf(-x)); }
static __device__ __forceinline__ float tanhfast(float x){ return 1.f-2.f/(1.f+__expf(2.f*x)); }

// ---- MALL-coherent primitives (sc0 sc1 = bypass L1+L2), proven round 3/5 ----
static __device__ __forceinline__ i32x4 ld16_cc(const void* p){
  i32x4 r; asm volatile("global_load_dwordx4 %0, %1, off sc0 sc1" : "=v"(r) : "v"(p) : "memory"); return r;
}
static __device__ __forceinline__ unsigned ld4_cc(const void* p){
  unsigned r; asm volatile("global_load_dword %0, %1, off sc0 sc1\ns_waitcnt vmcnt(0)" : "=v"(r) : "v"(p) : "memory"); return r;
}
static __device__ __forceinline__ void st4_cc(void* p, unsigned v){
  asm volatile("global_store_dword %0, %1, off sc0 sc1" :: "v"(p), "v"(v) : "memory");
}
static __device__ __forceinline__ void st8_cc(void* p, u32x2 v){
  asm volatile("global_store_dwordx2 %0, %1, off sc0 sc1" :: "v"(p), "v"(v) : "memory");
}

static __device__ __forceinline__ s16x8 cvt8(f32x4 a, f32x4 b){
  s16x8 r;
  r[0]=f2bf(a[0]); r[1]=f2bf(a[1]); r[2]=f2bf(a[2]); r[3]=f2bf(a[3]);
  r[4]=f2bf(b[0]); r[5]=f2bf(b[1]); r[6]=f2bf(b[2]); r[7]=f2bf(b[3]);
  return r;
}

// ===================== PRIMARY: tagged-h, flagless exchange =====================
__global__ __launch_bounds__(NTHREADS, 1)
void lstm_tag(const float* __restrict__ X,
              const float* __restrict__ Wf, const float* __restrict__ bfv,
              const float* __restrict__ Wi, const float* __restrict__ biv,
              const float* __restrict__ Wg, const float* __restrict__ bgv,
              const float* __restrict__ Wo, const float* __restrict__ bov,
              float* __restrict__ out,
              unsigned* __restrict__ htag)    // [2][128][256] u32: (tag<<16)|bf16
{
  const int bid = blockIdx.x;
  const int r   = bid & 7;        // batch group (rows r*16 .. r*16+15)
  const int csl = bid >> 3;       // column slice: h-cols [32*csl, 32*csl+32)
  const int tid = threadIdx.x;
  const int lane = tid & 63, wv = tid >> 6;
  const int grp = lane >> 4, l15 = lane & 15;
  const int r0 = r * 16;

  __shared__ short bfx[64 * 64 * 8];   // x-part B frags, 64 KB
  __shared__ float elds[4 * 16 * 36];  // per-wave epilogue bounce

  // ---- weights: x-part (k<256) -> LDS frags, h-part (k>=256) -> regs ----
  s16x8 bh[2][8];
  {
    const float* Wm[4] = {Wf, Wi, Wg, Wo};
    const int gate = l15 >> 2, jj = l15 & 3;
    const float* Wsrc = Wm[gate];
#pragma unroll
    for (int n2 = 0; n2 < 2; ++n2) {
      const int hc = csl * 32 + (wv * 2 + n2) * 4 + jj;
#pragma unroll
      for (int kk = 0; kk < 16; ++kk) {
        const float* p = Wsrc + (size_t)(kk * 32 + grp * 8) * DH + hc;
        s16x8 f;
#pragma unroll
        for (int s = 0; s < 8; ++s) f[s] = f2bf(p[(size_t)s * DH]);
        if (kk < 8) *(s16x8*)&bfx[(((wv * 2 + n2) * 8 + kk) * 64 + lane) * 8] = f;
        else        bh[n2][kk - 8] = f;
      }
    }
  }

  const int colg = csl * 32 + wv * 8 + 2 * grp;   // lane's 2 h-cols
  float bia[4][2];
  {
    const float* Bv[4] = {bfv, biv, bgv, bov};
#pragma unroll
    for (int g = 0; g < 4; ++g) { bia[g][0] = Bv[g][colg]; bia[g][1] = Bv[g][colg + 1]; }
  }
  __syncthreads();                 // bfx ready (read-only hereafter)

  // ---- preloop: x(0) -> regs, accx(0) ----
  f32x4 xr[16];
  {
    const float* xs0 = X + (size_t)(r0 + l15) * DIN + grp * 8;
#pragma unroll
    for (int kk = 0; kk < 8; ++kk) {
      xr[2 * kk]     = *(const f32x4*)(xs0 + kk * 32);
      xr[2 * kk + 1] = *(const f32x4*)(xs0 + kk * 32 + 4);
    }
  }
  f32x4 accx0 = {0.f,0.f,0.f,0.f}, accx1 = {0.f,0.f,0.f,0.f};
#pragma unroll
  for (int kk = 0; kk < 8; ++kk) {
    s16x8 fa = cvt8(xr[2 * kk], xr[2 * kk + 1]);
    s16x8 b0 = *(const s16x8*)&bfx[(((wv * 2 + 0) * 8 + kk) * 64 + lane) * 8];
    s16x8 b1 = *(const s16x8*)&bfx[(((wv * 2 + 1) * 8 + kk) * 64 + lane) * 8];
    accx0 = __builtin_amdgcn_mfma_f32_16x16x32_bf16(fa, b0, accx0, 0, 0, 0);
    accx1 = __builtin_amdgcn_mfma_f32_16x16x32_bf16(fa, b1, accx1, 0, 0, 0);
  }

  float cs0 = 0.f, cs1 = 0.f, h0s = 0.f, h1s = 0.f;

  for (int t = 0; t < T_STEPS; ++t) {
    // ---- flagless read of h(t): load tagged data, retry until all fresh ----
    const unsigned tte = (unsigned)t << 16;
    const unsigned* hb = htag + (size_t)(t & 1) * (BATCH * DH)
                       + (size_t)(r0 + l15) * DH + grp * 8;
    i32x4 hraw[16];
    while (1) {
#pragma unroll
      for (int q = 0; q < 8; ++q) {
        hraw[2 * q]     = ld16_cc(hb + q * 32);
        hraw[2 * q + 1] = ld16_cc(hb + q * 32 + 4);
      }
      asm volatile("s_waitcnt vmcnt(0)" ::: "memory");
      // each 8B half-chunk written by one dwordx2 -> checking u32 0,2 covers all
      unsigned bad = 0;
#pragma unroll
      for (int i2 = 0; i2 < 16; ++i2)
        bad |= (unsigned)(hraw[i2][0] ^ (int)tte) | (unsigned)(hraw[i2][2] ^ (int)tte);
      bad &= 0xFFFF0000u;
      if (__all((int)(bad == 0))) break;
    }
    __builtin_amdgcn_sched_barrier(0);

    // ---- unpack (v_perm) + h-part MFMAs on top of precomputed x-part ----
    f32x4 acc0 = accx0, acc1 = accx1;
#pragma unroll
    for (int q = 0; q < 8; ++q) {
      i32x4 hp;
      hp[0] = (int)__builtin_amdgcn_perm((unsigned)hraw[2*q][1],   (unsigned)hraw[2*q][0],   0x05040100u);
      hp[1] = (int)__builtin_amdgcn_perm((unsigned)hraw[2*q][3],   (unsigned)hraw[2*q][2],   0x05040100u);
      hp[2] = (int)__builtin_amdgcn_perm((unsigned)hraw[2*q+1][1], (unsigned)hraw[2*q+1][0], 0x05040100u);
      hp[3] = (int)__builtin_amdgcn_perm((unsigned)hraw[2*q+1][3], (unsigned)hraw[2*q+1][2], 0x05040100u);
      s16x8 ah = __builtin_bit_cast(s16x8, hp);
      acc0 = __builtin_amdgcn_mfma_f32_16x16x32_bf16(ah, bh[0][q], acc0, 0, 0, 0);
      acc1 = __builtin_amdgcn_mfma_f32_16x16x32_bf16(ah, bh[1][q], acc1, 0, 0, 0);
    }

    // ---- per-wave transpose bounce (intra-wave only) ----
#pragma unroll
    for (int rr = 0; rr < 4; ++rr) {
      float* eldsw = &elds[wv * 16 * 36];
      eldsw[(grp * 4 + rr) * 36 + l15]      = acc0[rr];
      eldsw[(grp * 4 + rr) * 36 + 16 + l15] = acc1[rr];
    }
    asm volatile("s_waitcnt lgkmcnt(0)" ::: "memory");
    __builtin_amdgcn_sched_barrier(0);
    float z0[4], z1[4];
    {
      const float* eldsw = &elds[wv * 16 * 36];
      const int hc0 = 2 * grp, hc1 = 2 * grp + 1;
#pragma unroll
      for (int g = 0; g < 4; ++g) {
        z0[g] = eldsw[l15 * 36 + ((hc0 >> 2) << 4) + 4 * g + (hc0 & 3)];
        z1[g] = eldsw[l15 * 36 + ((hc1 >> 2) << 4) + 4 * g + (hc1 & 3)];
      }
    }

    // ---- cell update (2 cells: row r0+l15, cols colg, colg+1) ----
    {
      float zf = z0[0] + bia[0][0], zi = z0[1] + bia[1][0];
      float zg = z0[2] + bia[2][0], zo = z0[3] + bia[3][0];
      cs0 = sigf(zf) * cs0 + sigf(zi) * tanhfast(zg);
      h0s = sigf(zo) * tanhfast(cs0);
    }
    {
      float zf = z1[0] + bia[0][1], zi = z1[1] + bia[1][1];
      float zg = z1[2] + bia[2][1], zo = z1[3] + bia[3][1];
      cs1 = sigf(zf) * cs1 + sigf(zi) * tanhfast(zg);
      h1s = sigf(zo) * tanhfast(cs1);
    }

    // ---- tagged h(t+1) store: ONE dwordx2, no ack, no barrier, no flag ----
    const int row = r0 + l15;
    {
      const unsigned ttw = (unsigned)(t + 1) << 16;
      u32x2 hpk;
      hpk[0] = (unsigned)(unsigned short)f2bf(h0s) | ttw;
      hpk[1] = (unsigned)(unsigned short)f2bf(h1s) | ttw;
      st8_cc(htag + (size_t)((t + 1) & 1) * (BATCH * DH) + (size_t)row * DH + colg, hpk);
    }

    // ---- shadow work: out store, x(t+1) load, x-part precompute ----
    {
      f32x2 ov; ov[0] = h0s; ov[1] = h1s;
      *(f32x2*)(out + ((size_t)t * BATCH + row) * DH + colg) = ov;
    }
    {
      const int tnx = (t + 1 < T_STEPS) ? t + 1 : T_STEPS - 1;
      const float* xs = X + ((size_t)tnx * BATCH + r0 + l15) * DIN + grp * 8;
#pragma unroll
      for (int kk = 0; kk < 8; ++kk) {
        xr[2 * kk]     = *(const f32x4*)(xs + kk * 32);
        xr[2 * kk + 1] = *(const f32x4*)(xs + kk * 32 + 4);
      }
    }
    accx0 = (f32x4){0.f,0.f,0.f,0.f}; accx1 = (f32x4){0.f,0.f,0.f,0.f};
#pragma unroll
    for (int kk = 0; kk < 8; ++kk) {
      s16x8 fa = cvt8(xr[2 * kk], xr[2 * kk + 1]);
      s16x8 b0 = *(const s16x8*)&bfx[(((wv * 2 + 0) * 8 + kk) * 64 + lane) * 8];
      s16x8 b1 = *(const s16x8*)&bfx[(((wv * 2 + 1) * 8 + kk) * 64 + lane) * 8];
      accx0 = __builtin_amdgcn_mfma_f32_16x16x32_bf16(fa, b0, accx0, 0, 0, 0);
      accx1 = __builtin_amdgcn_mfma_f32_16x16x32_bf16(fa, b1, accx1, 0, 0, 0);
    }
  }

  // ---- final hx, cx (fp32, from regs; htag in d_ws -> no aliasing, no sync) ----
  {
    const size_t base = (size_t)T_STEPS * BATCH * DH;
    const size_t idx  = (size_t)(r0 + l15) * DH + colg;
    out[base + idx]     = h0s;
    out[base + idx + 1] = h1s;
    out[base + BATCH * DH + idx]     = cs0;
    out[base + BATCH * DH + idx + 1] = cs1;
  }
}

// ===================== FALLBACK (round-3/5 proven, flags in d_out tail) =====================
__global__ __launch_bounds__(NTHREADS, 1)
void lstm_rc_fb(const float* __restrict__ X,
                const float* __restrict__ Wf, const float* __restrict__ bfv,
                const float* __restrict__ Wi, const float* __restrict__ biv,
                const float* __restrict__ Wg, const float* __restrict__ bgv,
                const float* __restrict__ Wo, const float* __restrict__ bov,
                float* __restrict__ out,
                unsigned short* __restrict__ hbuf,
                unsigned int* __restrict__ flags,
                int needEnd)
{
  const int bid = blockIdx.x;
  const int r   = bid & 7;
  const int csl = bid >> 3;
  const int tid = threadIdx.x;
  const int lane = tid & 63, wv = tid >> 6;
  const int grp = lane >> 4, l15 = lane & 15;
  const int r0 = r * 16;

  __shared__ short bfx[64 * 64 * 8];
  __shared__ float elds[4 * 16 * 36];

  s16x8 bh[2][8];
  {
    const float* Wm[4] = {Wf, Wi, Wg, Wo};
    const int gate = l15 >> 2, jj = l15 & 3;
    const float* Wsrc = Wm[gate];
#pragma unroll
    for (int n2 = 0; n2 < 2; ++n2) {
      const int hc = csl * 32 + (wv * 2 + n2) * 4 + jj;
#pragma unroll
      for (int kk = 0; kk < 16; ++kk) {
        const float* p = Wsrc + (size_t)(kk * 32 + grp * 8) * DH + hc;
        s16x8 f;
#pragma unroll
        for (int s = 0; s < 8; ++s) f[s] = f2bf(p[(size_t)s * DH]);
        if (kk < 8) *(s16x8*)&bfx[(((wv * 2 + n2) * 8 + kk) * 64 + lane) * 8] = f;
        else        bh[n2][kk - 8] = f;
      }
    }
  }

  const int colg = csl * 32 + wv * 8 + 2 * grp;
  float bia[4][2];
  {
    const float* Bv[4] = {bfv, biv, bgv, bov};
#pragma unroll
    for (int g = 0; g < 4; ++g) { bia[g][0] = Bv[g][colg]; bia[g][1] = Bv[g][colg + 1]; }
  }
  __syncthreads();

  f32x4 xr[16];
  {
    const float* xs0 = X + (size_t)(r0 + l15) * DIN + grp * 8;
#pragma unroll
    for (int kk = 0; kk < 8; ++kk) {
      xr[2 * kk]     = *(const f32x4*)(xs0 + kk * 32);
      xr[2 * kk + 1] = *(const f32x4*)(xs0 + kk * 32 + 4);
    }
  }
  f32x4 accx0 = {0.f,0.f,0.f,0.f}, accx1 = {0.f,0.f,0.f,0.f};
#pragma unroll
  for (int kk = 0; kk < 8; ++kk) {
    s16x8 fa = cvt8(xr[2 * kk], xr[2 * kk + 1]);
    s16x8 b0 = *(const s16x8*)&bfx[(((wv * 2 + 0) * 8 + kk) * 64 + lane) * 8];
    s16x8 b1 = *(const s16x8*)&bfx[(((wv * 2 + 1) * 8 + kk) * 64 + lane) * 8];
    accx0 = __builtin_amdgcn_mfma_f32_16x16x32_bf16(fa, b0, accx0, 0, 0, 0);
    accx1 = __builtin_amdgcn_mfma_f32_16x16x32_bf16(fa, b1, accx1, 0, 0, 0);
  }

  unsigned* myflag = flags + (r * 32 + csl);
  const unsigned* pollp = flags + (r * 32 + (lane & 7));
  float* eldsw = &elds[wv * 16 * 36];
  float cs0 = 0.f, cs1 = 0.f, h0s = 0.f, h1s = 0.f;

  for (int t = 0; t < T_STEPS; ++t) {
    while (1) {
      unsigned v = ld4_cc(pollp);
      if (__all((int)(v >= (unsigned)t))) break;
    }
    __builtin_amdgcn_sched_barrier(0);

    const unsigned short* hr = hbuf + (size_t)(t & 1) * (BATCH * DH)
                             + (size_t)(r0 + l15) * DH + grp * 8;
    i32x4 hraw[8];
#pragma unroll
    for (int q = 0; q < 8; ++q) hraw[q] = ld16_cc(hr + q * 32);
    asm volatile("s_waitcnt vmcnt(0)" ::: "memory");
    __builtin_amdgcn_sched_barrier(0);

    f32x4 acc0 = accx0, acc1 = accx1;
#pragma unroll
    for (int q = 0; q < 8; ++q) {
      s16x8 ah = __builtin_bit_cast(s16x8, hraw[q]);
      acc0 = __builtin_amdgcn_mfma_f32_16x16x32_bf16(ah, bh[0][q], acc0, 0, 0, 0);
      acc1 = __builtin_amdgcn_mfma_f32_16x16x32_bf16(ah, bh[1][q], acc1, 0, 0, 0);
    }

#pragma unroll
    for (int rr = 0; rr < 4; ++rr) {
      eldsw[(grp * 4 + rr) * 36 + l15]      = acc0[rr];
      eldsw[(grp * 4 + rr) * 36 + 16 + l15] = acc1[rr];
    }
    asm volatile("s_waitcnt lgkmcnt(0)" ::: "memory");
    __builtin_amdgcn_sched_barrier(0);
    float z0[4], z1[4];
    const int hc0 = 2 * grp, hc1 = 2 * grp + 1;
#pragma unroll
    for (int g = 0; g < 4; ++g) {
      z0[g] = eldsw[l15 * 36 + ((hc0 >> 2) << 4) + 4 * g + (hc0 & 3)];
      z1[g] = eldsw[l15 * 36 + ((hc1 >> 2) << 4) + 4 * g + (hc1 & 3)];
    }
    {
      float zf = z0[0] + bia[0][0], zi = z0[1] + bia[1][0];
      float zg = z0[2] + bia[2][0], zo = z0[3] + bia[3][0];
      cs0 = sigf(zf) * cs0 + sigf(zi) * tanhfast(zg);
      h0s = sigf(zo) * tanhfast(cs0);
    }
    {
      float zf = z1[0] + bia[0][1], zi = z1[1] + bia[1][1];
      float zg = z1[2] + bia[2][1], zo = z1[3] + bia[3][1];
      cs1 = sigf(zf) * cs1 + sigf(zi) * tanhfast(zg);
      h1s = sigf(zo) * tanhfast(cs1);
    }
    const int row = r0 + l15;
    {
      unsigned hpk = (unsigned)(unsigned short)f2bf(h0s)
                   | ((unsigned)(unsigned short)f2bf(h1s) << 16);
      st4_cc(hbuf + (size_t)((t + 1) & 1) * (BATCH * DH)
             + (size_t)row * DH + colg, hpk);
    }
    asm volatile("s_waitcnt vmcnt(0)" ::: "memory");
    __syncthreads();
    if (tid == 0) st4_cc(myflag, (unsigned)(t + 1));

    {
      f32x2 ov; ov[0] = h0s; ov[1] = h1s;
      *(f32x2*)(out + ((size_t)t * BATCH + row) * DH + colg) = ov;
    }
    {
      const int tnx = (t + 1 < T_STEPS) ? t + 1 : T_STEPS - 1;
      const float* xs = X + ((size_t)tnx * BATCH + r0 + l15) * DIN + grp * 8;
#pragma unroll
      for (int kk = 0; kk < 8; ++kk) {
        xr[2 * kk]     = *(const f32x4*)(xs + kk * 32);
        xr[2 * kk + 1] = *(const f32x4*)(xs + kk * 32 + 4);
      }
    }
    accx0 = (f32x4){0.f,0.f,0.f,0.f}; accx1 = (f32x4){0.f,0.f,0.f,0.f};
#pragma unroll
    for (int kk = 0; kk < 8; ++kk) {
      s16x8 fa = cvt8(xr[2 * kk], xr[2 * kk + 1]);
      s16x8 b0 = *(const s16x8*)&bfx[(((wv * 2 + 0) * 8 + kk) * 64 + lane) * 8];
      s16x8 b1 = *(const s16x8*)&bfx[(((wv * 2 + 1) * 8 + kk) * 64 + lane) * 8];
      accx0 = __builtin_amdgcn_mfma_f32_16x16x32_bf16(fa, b0, accx0, 0, 0, 0);
      accx1 = __builtin_amdgcn_mfma_f32_16x16x32_bf16(fa, b1, accx1, 0, 0, 0);
    }
  }

  if (needEnd) {
    if (wv == 0) {
      const unsigned* fp = flags + ((lane >> 3) * 32 + (lane & 7));
      while (ld4_cc(fp) < (unsigned)T_STEPS) __builtin_amdgcn_s_sleep(1);
    }
    __syncthreads();
  }
  {
    const size_t base = (size_t)T_STEPS * BATCH * DH;
    const size_t idx  = (size_t)(r0 + l15) * DH + colg;
    out[base + idx]     = h0s;
    out[base + idx + 1] = h1s;
    out[base + BATCH * DH + idx]     = cs0;
    out[base + BATCH * DH + idx + 1] = cs1;
  }
}

extern "C" void kernel_launch(void* const* d_in, const int* in_sizes, int n_in,
                              void* d_out, int out_size, void* d_ws, size_t ws_size,
                              hipStream_t stream) {
  const float* X   = (const float*)d_in[0];
  const float* Wf  = (const float*)d_in[1];
  const float* bf_ = (const float*)d_in[2];
  const float* Wi  = (const float*)d_in[3];
  const float* bi_ = (const float*)d_in[4];
  const float* Wg  = (const float*)d_in[5];
  const float* bg_ = (const float*)d_in[6];
  const float* Wo  = (const float*)d_in[7];
  const float* bo_ = (const float*)d_in[8];
  float* out = (float*)d_out;

  const size_t tagbytes = (size_t)2 * BATCH * DH * 4;   // 262144
  if (ws_size >= tagbytes) {
    unsigned* htag = (unsigned*)d_ws;
    hipMemsetAsync(d_ws, 0, tagbytes, stream);          // tag 0 == h(0) == 0.0
    lstm_tag<<<NWG, NTHREADS, 0, stream>>>(X, Wf, bf_, Wi, bi_, Wg, bg_,
                                           Wo, bo_, out, htag);
    return;
  }

  // FALLBACK (never expected: ws_size >= 1 MiB observed in round 7)
  const size_t hbytes = (size_t)2 * BATCH * DH * 2;
  const size_t fbytes = 2048;
  unsigned char* tail = (unsigned char*)d_out + (size_t)T_STEPS * BATCH * DH * 4;
  unsigned short* hbuf = (unsigned short*)tail;
  unsigned int* flags  = (unsigned int*)(tail + hbytes);
  hipMemsetAsync(tail, 0, hbytes + fbytes, stream);
  lstm_rc_fb<<<NWG, NTHREADS, 0, stream>>>(X, Wf, bf_, Wi, bi_, Wg, bg_,
                                           Wo, bo_, out, hbuf, flags, 1);
}

// Round 10
// 4301.955 us; speedup vs baseline: 2.9221x; 1.1444x over previous
//
#include <hip/hip_runtime.h>
#include <hip/hip_bf16.h>

typedef short s16x8 __attribute__((ext_vector_type(8)));
typedef int   i32x4 __attribute__((ext_vector_type(4)));
typedef float f32x4 __attribute__((ext_vector_type(4)));
typedef float f32x2 __attribute__((ext_vector_type(2)));

#define T_STEPS 1024
#define BATCH   128
#define DIN     256
#define DH      256
#define NWG     64     // 8 batch-groups (x16 rows) x 8 col-slices (x32 h-cols)
#define NTHREADS 256

static __device__ __forceinline__ short f2bf(float f){ return __builtin_bit_cast(short,(__bf16)f); }
static __device__ __forceinline__ float sigf(float x){ return 1.f/(1.f+__expf(-x)); }
static __device__ __forceinline__ float tanhfast(float x){ return 1.f-2.f/(1.f+__expf(2.f*x)); }

// ---- MALL-coherent primitives (sc0 sc1 = bypass L1+L2; proven r3/r5/r6/r8) ----
static __device__ __forceinline__ i32x4 ld16_cc(const void* p){
  i32x4 r; asm volatile("global_load_dwordx4 %0, %1, off sc0 sc1" : "=v"(r) : "v"(p) : "memory"); return r;
}
static __device__ __forceinline__ unsigned ld4_cc(const void* p){
  unsigned r; asm volatile("global_load_dword %0, %1, off sc0 sc1\ns_waitcnt vmcnt(0)" : "=v"(r) : "v"(p) : "memory"); return r;
}
static __device__ __forceinline__ void st4_cc(void* p, unsigned v){
  asm volatile("global_store_dword %0, %1, off sc0 sc1" :: "v"(p), "v"(v) : "memory");
}
static __device__ __forceinline__ void st8_p(void* p, f32x2 v){
  asm volatile("global_store_dwordx2 %0, %1, off" :: "v"(p), "v"(v) : "memory");
}

static __device__ __forceinline__ s16x8 cvt8(f32x4 a, f32x4 b){
  s16x8 r;
  r[0]=f2bf(a[0]); r[1]=f2bf(a[1]); r[2]=f2bf(a[2]); r[3]=f2bf(a[3]);
  r[4]=f2bf(b[0]); r[5]=f2bf(b[1]); r[6]=f2bf(b[2]); r[7]=f2bf(b[3]);
  return r;
}

// Zero-barrier per-step engine:
//   poll 32 per-wave flags -> issue h loads (cc) -> stage x(t+1)->LDS ->
//   x-MFMAs (cover h RT) -> vmcnt(0) -> h-MFMAs -> per-wave epilogue ->
//   h-store(cc) + out-store -> vmcnt(1) -> publish own wave flag -> x(t+2) prefetch.
// Wave skew is bounded by the poll (a wave passes poll(t) only after every wave
// of the group published t), which makes the unbarriered LDS staging safe:
// buffer b is re-staged only after all waves provably finished reading it.
__global__ __launch_bounds__(NTHREADS, 1)
void lstm_v10(const float* __restrict__ X,
              const float* __restrict__ Wf, const float* __restrict__ bfv,
              const float* __restrict__ Wi, const float* __restrict__ biv,
              const float* __restrict__ Wg, const float* __restrict__ bgv,
              const float* __restrict__ Wo, const float* __restrict__ bov,
              float* __restrict__ out,
              unsigned short* __restrict__ hbuf,   // [2][128][256] bf16 bits
              unsigned int* __restrict__ flags,    // [8 g][8 csl][4 wv]
              int needEnd)
{
  const int bid = blockIdx.x;
  const int g   = bid & 7;        // batch group (rows g*16 .. g*16+15)
  const int csl = bid >> 3;       // column slice: h-cols [32*csl, 32*csl+32)
  const int tid = threadIdx.x;
  const int lane = tid & 63, wv = tid >> 6;
  const int grp = lane >> 4, l15 = lane & 15;
  const int r0 = g * 16;

  __shared__ short bfx_unused[4];            // (keep LDS layout simple)
  __shared__ short a_lds[2 * 32 * 16 * 8];   // x A-frag staging, dbuf, 16 KB
  __shared__ float elds[4 * 16 * 36];        // PER-WAVE epilogue bounce, 9 KB
  (void)bfx_unused;

  // ---- weights -> registers (B frags), r3 layout: bfr[n2][kk] ----
  s16x8 bfr[2][16];
  {
    const float* Wm[4] = {Wf, Wi, Wg, Wo};
    const int gate = l15 >> 2, jj = l15 & 3;
    const float* Wsrc = Wm[gate];
#pragma unroll
    for (int n2 = 0; n2 < 2; ++n2) {
      const int hc = csl * 32 + (wv * 2 + n2) * 4 + jj;
#pragma unroll
      for (int kk = 0; kk < 16; ++kk) {
        const float* p = Wsrc + (size_t)(kk * 32 + grp * 8) * DH + hc;
        s16x8 f;
#pragma unroll
        for (int s = 0; s < 8; ++s) f[s] = f2bf(p[(size_t)s * DH]);
        bfr[n2][kk] = f;
      }
    }
  }

  // per-lane epilogue cells (r5-proven): row r0+l15, cols colg, colg+1
  const int colg = csl * 32 + wv * 8 + 2 * grp;
  float bia[4][2];
  {
    const float* Bv[4] = {bfv, biv, bgv, bov};
#pragma unroll
    for (int q = 0; q < 4; ++q) { bia[q][0] = Bv[q][colg]; bia[q][1] = Bv[q][colg + 1]; }
  }

  // X staging roles (all 4 waves cooperate; safety via poll-bounded skew)
  const int xrow = tid & 15, xseg = tid >> 4;

  // preloop: stage x(0) -> a_lds[0]; prefetch x(1) -> regs
  f32x4 xp0, xp1, xp2, xp3;
  {
    const float* xs = X + (size_t)(r0 + xrow) * DIN + xseg * 16;
    s16x8 lo = cvt8(*(const f32x4*)xs, *(const f32x4*)(xs + 4));
    s16x8 hi = cvt8(*(const f32x4*)(xs + 8), *(const f32x4*)(xs + 12));
    *(s16x8*)&a_lds[((2 * xseg + 0) * 16 + xrow) * 8] = lo;
    *(s16x8*)&a_lds[((2 * xseg + 1) * 16 + xrow) * 8] = hi;
    const float* xn = X + ((size_t)1 * BATCH + r0 + xrow) * DIN + xseg * 16;
    xp0 = *(const f32x4*)xn;       xp1 = *(const f32x4*)(xn + 4);
    xp2 = *(const f32x4*)(xn + 8); xp3 = *(const f32x4*)(xn + 12);
  }
  __syncthreads();                 // one-time: buf0 staged before loop

  unsigned* myflag = flags + (g * 32 + csl * 4 + wv);
  const unsigned* pollp = flags + (g * 32 + (lane & 31));
  float* eldsw = &elds[wv * 16 * 36];
  float cs0 = 0.f, cs1 = 0.f, h0s = 0.f, h1s = 0.f;

  for (int t = 0; t < T_STEPS; ++t) {
    // ---- 1. poll the group's 32 per-wave flags (one cacheline) ----
    while (1) {
      unsigned v = ld4_cc(pollp);
      if (__all((int)(v >= (unsigned)t))) break;
    }
    __builtin_amdgcn_sched_barrier(0);

    // ---- 2. issue h(t) loads (MALL) ----
    const unsigned short* hr = hbuf + (size_t)(t & 1) * (BATCH * DH)
                             + (size_t)(r0 + l15) * DH + grp * 8;
    i32x4 hraw[8];
#pragma unroll
    for (int q = 0; q < 8; ++q) hraw[q] = ld16_cc(hr + q * 32);

    // ---- 3. stage x(t+1) regs -> a_lds[(t+1)&1] ----
    {
      short* ab = a_lds + ((t + 1) & 1) * (32 * 16 * 8);
      s16x8 lo = cvt8(xp0, xp1), hi = cvt8(xp2, xp3);
      *(s16x8*)&ab[((2 * xseg + 0) * 16 + xrow) * 8] = lo;
      *(s16x8*)&ab[((2 * xseg + 1) * 16 + xrow) * 8] = hi;
    }

    // ---- 4. x-part MFMAs from a_lds[t&1] (covers h-load RT) ----
    const short* ar = a_lds + (t & 1) * (32 * 16 * 8);
    f32x4 acc0 = {0.f,0.f,0.f,0.f}, acc1 = {0.f,0.f,0.f,0.f};
#pragma unroll
    for (int kk = 0; kk < 8; ++kk) {
      s16x8 a = *(const s16x8*)&ar[((kk * 4 + grp) * 16 + l15) * 8];
      acc0 = __builtin_amdgcn_mfma_f32_16x16x32_bf16(a, bfr[0][kk], acc0, 0, 0, 0);
      acc1 = __builtin_amdgcn_mfma_f32_16x16x32_bf16(a, bfr[1][kk], acc1, 0, 0, 0);
    }

    // ---- 5. h-part MFMAs ----
    asm volatile("s_waitcnt vmcnt(0)" ::: "memory");
    __builtin_amdgcn_sched_barrier(0);
#pragma unroll
    for (int q = 0; q < 8; ++q) {
      s16x8 ah = __builtin_bit_cast(s16x8, hraw[q]);
      acc0 = __builtin_amdgcn_mfma_f32_16x16x32_bf16(ah, bfr[0][8 + q], acc0, 0, 0, 0);
      acc1 = __builtin_amdgcn_mfma_f32_16x16x32_bf16(ah, bfr[1][8 + q], acc1, 0, 0, 0);
    }

    // ---- 6. per-wave epilogue (r5-proven; no cross-wave sharing, no barrier) ----
#pragma unroll
    for (int rr = 0; rr < 4; ++rr) {
      eldsw[(grp * 4 + rr) * 36 + l15]      = acc0[rr];
      eldsw[(grp * 4 + rr) * 36 + 16 + l15] = acc1[rr];
    }
    asm volatile("s_waitcnt lgkmcnt(0)" ::: "memory");
    __builtin_amdgcn_sched_barrier(0);
    float z0[4], z1[4];
    const int hc0 = 2 * grp, hc1 = 2 * grp + 1;
#pragma unroll
    for (int q = 0; q < 4; ++q) {
      z0[q] = eldsw[l15 * 36 + ((hc0 >> 2) << 4) + 4 * q + (hc0 & 3)];
      z1[q] = eldsw[l15 * 36 + ((hc1 >> 2) << 4) + 4 * q + (hc1 & 3)];
    }
    {
      float zf = z0[0] + bia[0][0], zi = z0[1] + bia[1][0];
      float zg = z0[2] + bia[2][0], zo = z0[3] + bia[3][0];
      cs0 = sigf(zf) * cs0 + sigf(zi) * tanhfast(zg);
      h0s = sigf(zo) * tanhfast(cs0);
    }
    {
      float zf = z1[0] + bia[0][1], zi = z1[1] + bia[1][1];
      float zg = z1[2] + bia[2][1], zo = z1[3] + bia[3][1];
      cs1 = sigf(zf) * cs1 + sigf(zi) * tanhfast(zg);
      h1s = sigf(zo) * tanhfast(cs1);
    }

    // ---- 7. h-store (cc, oldest) + out-store (plain, younger) ----
    const int row = r0 + l15;
    {
      unsigned hpk = (unsigned)(unsigned short)f2bf(h0s)
                   | ((unsigned)(unsigned short)f2bf(h1s) << 16);
      st4_cc(hbuf + (size_t)((t + 1) & 1) * (BATCH * DH)
             + (size_t)row * DH + colg, hpk);
      f32x2 ov; ov[0] = h0s; ov[1] = h1s;
      st8_p(out + ((size_t)t * BATCH + row) * DH + colg, ov);
    }

    // ---- 8. ack h-store only (out-store stays in flight), publish wave flag ----
    asm volatile("s_waitcnt vmcnt(1)" ::: "memory");
    if (lane == 0) st4_cc(myflag, (unsigned)(t + 1));

    // ---- 9. shadow: prefetch x(t+2) ----
    {
      const int tp = (t + 2 < T_STEPS) ? t + 2 : T_STEPS - 1;
      const float* xs = X + ((size_t)tp * BATCH + r0 + xrow) * DIN + xseg * 16;
      xp0 = *(const f32x4*)xs;       xp1 = *(const f32x4*)(xs + 4);
      xp2 = *(const f32x4*)(xs + 8); xp3 = *(const f32x4*)(xs + 12);
    }
  }

  // ---- final hx, cx (fp32, from registers) ----
  if (needEnd) {
    // buffers alias d_out tail: wait until every wave of every group finished
    const unsigned* fp = flags + tid;      // 256 flags, 256 threads
    while (ld4_cc(fp) < (unsigned)T_STEPS) __builtin_amdgcn_s_sleep(1);
    __syncthreads();
  }
  {
    const size_t base = (size_t)T_STEPS * BATCH * DH;
    const size_t idx  = (size_t)(r0 + l15) * DH + colg;
    out[base + idx]     = h0s;
    out[base + idx + 1] = h1s;
    out[base + BATCH * DH + idx]     = cs0;
    out[base + BATCH * DH + idx + 1] = cs1;
  }
}

extern "C" void kernel_launch(void* const* d_in, const int* in_sizes, int n_in,
                              void* d_out, int out_size, void* d_ws, size_t ws_size,
                              hipStream_t stream) {
  const float* X   = (const float*)d_in[0];
  const float* Wf  = (const float*)d_in[1];
  const float* bf_ = (const float*)d_in[2];
  const float* Wi  = (const float*)d_in[3];
  const float* bi_ = (const float*)d_in[4];
  const float* Wg  = (const float*)d_in[5];
  const float* bg_ = (const float*)d_in[6];
  const float* Wo  = (const float*)d_in[7];
  const float* bo_ = (const float*)d_in[8];
  float* out = (float*)d_out;

  const size_t hbytes = (size_t)2 * BATCH * DH * 2;   // 131072
  const size_t fbytes = 1024;                          // 256 flags
  unsigned short* hbuf;
  unsigned int*   flags;
  int needEnd;
  if (ws_size >= hbytes + fbytes) {
    hbuf  = (unsigned short*)d_ws;
    flags = (unsigned int*)((unsigned char*)d_ws + hbytes);
    needEnd = 0;
    hipMemsetAsync(d_ws, 0, hbytes + fbytes, stream);
  } else {
    unsigned char* tail = (unsigned char*)d_out + (size_t)T_STEPS * BATCH * DH * 4;
    hbuf  = (unsigned short*)tail;
    flags = (unsigned int*)(tail + hbytes);
    needEnd = 1;
    hipMemsetAsync(tail, 0, hbytes + fbytes, stream);
  }

  lstm_v10<<<NWG, NTHREADS, 0, stream>>>(X, Wf, bf_, Wi, bi_, Wg, bg_,
                                         Wo, bo_, out, hbuf, flags, needEnd);
}

// Round 11
// 3760.851 us; speedup vs baseline: 3.3425x; 1.1439x over previous
//
#include <hip/hip_runtime.h>
#include <hip/hip_bf16.h>

typedef short s16x8 __attribute__((ext_vector_type(8)));
typedef int   i32x4 __attribute__((ext_vector_type(4)));
typedef unsigned u32x2 __attribute__((ext_vector_type(2)));
typedef float f32x4 __attribute__((ext_vector_type(4)));
typedef float f32x2 __attribute__((ext_vector_type(2)));

#define T_STEPS 1024
#define BATCH   128
#define DIN     256
#define DH      256
#define NWG     64     // 8 batch-groups (x16 rows) x 8 col-slices (x32 h-cols)
#define NTHREADS 256

static __device__ __forceinline__ short f2bf(float f){ return __builtin_bit_cast(short,(__bf16)f); }
static __device__ __forceinline__ float sigf(float x){ return 1.f/(1.f+__expf(-x)); }
static __device__ __forceinline__ float tanhfast(float x){ return 1.f-2.f/(1.f+__expf(2.f*x)); }

// ---- MALL-coherent primitives (sc0 sc1 = bypass L1+L2; proven r3/r5/r8/r10) ----
static __device__ __forceinline__ i32x4 ld16_cc(const void* p){
  i32x4 r; asm volatile("global_load_dwordx4 %0, %1, off sc0 sc1" : "=v"(r) : "v"(p) : "memory"); return r;
}
static __device__ __forceinline__ unsigned ld4_cc(const void* p){
  unsigned r; asm volatile("global_load_dword %0, %1, off sc0 sc1\ns_waitcnt vmcnt(0)" : "=v"(r) : "v"(p) : "memory"); return r;
}
static __device__ __forceinline__ void st4_cc(void* p, unsigned v){
  asm volatile("global_store_dword %0, %1, off sc0 sc1" :: "v"(p), "v"(v) : "memory");
}
static __device__ __forceinline__ void st8t_cc(void* p, u32x2 v){
  asm volatile("global_store_dwordx2 %0, %1, off sc0 sc1" :: "v"(p), "v"(v) : "memory");
}
static __device__ __forceinline__ void st8_p(void* p, f32x2 v){
  asm volatile("global_store_dwordx2 %0, %1, off" :: "v"(p), "v"(v) : "memory");
}

static __device__ __forceinline__ s16x8 cvt8(f32x4 a, f32x4 b){
  s16x8 r;
  r[0]=f2bf(a[0]); r[1]=f2bf(a[1]); r[2]=f2bf(a[2]); r[3]=f2bf(a[3]);
  r[4]=f2bf(b[0]); r[5]=f2bf(b[1]); r[6]=f2bf(b[2]); r[7]=f2bf(b[3]);
  return r;
}

// =============== PRIMARY: r3 skeleton, hint-flag + tag-validated h, no store-ack ===============
__global__ __launch_bounds__(NTHREADS, 1)
void lstm_v11(const float* __restrict__ X,
              const float* __restrict__ Wf, const float* __restrict__ bfv,
              const float* __restrict__ Wi, const float* __restrict__ biv,
              const float* __restrict__ Wg, const float* __restrict__ bgv,
              const float* __restrict__ Wo, const float* __restrict__ bov,
              float* __restrict__ out,
              unsigned* __restrict__ htag,     // [2][128][256] u32: (tag<<16)|bf16
              unsigned* __restrict__ flags)    // [8 g][32] hint flags (1/WG used)
{
  const int bid = blockIdx.x;
  const int g   = bid & 7;        // batch group (rows g*16 .. g*16+15)
  const int csl = bid >> 3;       // column slice: h-cols [32*csl, 32*csl+32)
  const int tid = threadIdx.x;
  const int lane = tid & 63, wv = tid >> 6;
  const int grp = lane >> 4, l15 = lane & 15;
  const int r0 = g * 16;

  __shared__ short a_lds[2 * 32 * 16 * 8];   // x A-frag staging, dbuf, 16 KB
  __shared__ float elds[16 * 132];           // cross-wave epilogue bounce (r3)

  // ---- weights -> registers (B frags), r3 layout: bfr[n2][kk], kk<8 = x, kk>=8 = h ----
  s16x8 bfr[2][16];
  {
    const float* Wm[4] = {Wf, Wi, Wg, Wo};
    const int gate = l15 >> 2, jj = l15 & 3;
    const float* Wsrc = Wm[gate];
#pragma unroll
    for (int n2 = 0; n2 < 2; ++n2) {
      const int hc = csl * 32 + (wv * 2 + n2) * 4 + jj;
#pragma unroll
      for (int kk = 0; kk < 16; ++kk) {
        const float* p = Wsrc + (size_t)(kk * 32 + grp * 8) * DH + hc;
        s16x8 f;
#pragma unroll
        for (int s = 0; s < 8; ++s) f[s] = f2bf(p[(size_t)s * DH]);
        bfr[n2][kk] = f;
      }
    }
  }

  // r3 epilogue roles: row r0+erow, local col pair {2*j2, 2*j2+1}
  const int erow = tid >> 4;
  const int j2   = tid & 15;
  const int ntl  = j2 >> 1;
  const int jjl  = (j2 & 1) * 2;
  float bia[4][2];
  {
    const float* Bv[4] = {bfv, biv, bgv, bov};
#pragma unroll
    for (int q = 0; q < 4; ++q) {
      bia[q][0] = Bv[q][csl * 32 + 2 * j2];
      bia[q][1] = Bv[q][csl * 32 + 2 * j2 + 1];
    }
  }

  // X staging roles
  const int xrow = tid & 15, xseg = tid >> 4;
  f32x4 xp0, xp1, xp2, xp3;
  {
    const float* xs = X + (size_t)(r0 + xrow) * DIN + xseg * 16;
    s16x8 lo = cvt8(*(const f32x4*)xs, *(const f32x4*)(xs + 4));
    s16x8 hi = cvt8(*(const f32x4*)(xs + 8), *(const f32x4*)(xs + 12));
    *(s16x8*)&a_lds[((2 * xseg + 0) * 16 + xrow) * 8] = lo;
    *(s16x8*)&a_lds[((2 * xseg + 1) * 16 + xrow) * 8] = hi;
    const float* xn = X + ((size_t)1 * BATCH + r0 + xrow) * DIN + xseg * 16;
    xp0 = *(const f32x4*)xn;       xp1 = *(const f32x4*)(xn + 4);
    xp2 = *(const f32x4*)(xn + 8); xp3 = *(const f32x4*)(xn + 12);
  }
  __syncthreads();

  unsigned* myflag = flags + (g * 32 + csl);
  const unsigned* pollp = flags + (g * 32 + (lane & 7));
  float cs0 = 0.f, cs1 = 0.f, h0s = 0.f, h1s = 0.f;

  for (int t = 0; t < T_STEPS; ++t) {
    const unsigned tte = (unsigned)t << 16;

    // ---- 1. poll 8 WG hint flags (one cacheline) ----
    while (1) {
      unsigned v = ld4_cc(pollp);
      if (__all((int)(v >= (unsigned)t))) break;
    }
    __builtin_amdgcn_sched_barrier(0);

    // ---- 2. issue tagged h(t) loads ----
    const unsigned* hb = htag + (size_t)(t & 1) * (BATCH * DH)
                       + (size_t)(r0 + l15) * DH + grp * 8;
    i32x4 hraw[16];
#pragma unroll
    for (int q = 0; q < 8; ++q) {
      hraw[2 * q]     = ld16_cc(hb + q * 32);
      hraw[2 * q + 1] = ld16_cc(hb + q * 32 + 4);
    }

    // ---- 3. stage x(t+1) regs -> a_lds[(t+1)&1] (buffer provably free: see B1/B2) ----
    {
      short* ab = a_lds + ((t + 1) & 1) * (32 * 16 * 8);
      s16x8 lo = cvt8(xp0, xp1), hi = cvt8(xp2, xp3);
      *(s16x8*)&ab[((2 * xseg + 0) * 16 + xrow) * 8] = lo;
      *(s16x8*)&ab[((2 * xseg + 1) * 16 + xrow) * 8] = hi;
    }

    // ---- 4. x-part MFMAs from a_lds[t&1] (covers h-load RT) ----
    const short* ar = a_lds + (t & 1) * (32 * 16 * 8);
    f32x4 acc0 = {0.f,0.f,0.f,0.f}, acc1 = {0.f,0.f,0.f,0.f};
#pragma unroll
    for (int kk = 0; kk < 8; ++kk) {
      s16x8 a = *(const s16x8*)&ar[((kk * 4 + grp) * 16 + l15) * 8];
      acc0 = __builtin_amdgcn_mfma_f32_16x16x32_bf16(a, bfr[0][kk], acc0, 0, 0, 0);
      acc1 = __builtin_amdgcn_mfma_f32_16x16x32_bf16(a, bfr[1][kk], acc1, 0, 0, 0);
    }

    // ---- 5. validate tags; retry (rare: flag is ~1 RT older than our load) ----
    asm volatile("s_waitcnt vmcnt(0)" ::: "memory");
    __builtin_amdgcn_sched_barrier(0);
    {
      int guardo = 1 << 16;
      while (1) {
        unsigned bad = 0;
#pragma unroll
        for (int i = 0; i < 16; ++i)
          bad |= (unsigned)(hraw[i][0] ^ (int)tte) | (unsigned)(hraw[i][1] ^ (int)tte)
               | (unsigned)(hraw[i][2] ^ (int)tte) | (unsigned)(hraw[i][3] ^ (int)tte);
        bad &= 0xFFFF0000u;
        if (__all((int)(bad == 0))) break;
        if (--guardo < 0) break;
#pragma unroll
        for (int q = 0; q < 8; ++q) {
          hraw[2 * q]     = ld16_cc(hb + q * 32);
          hraw[2 * q + 1] = ld16_cc(hb + q * 32 + 4);
        }
        asm volatile("s_waitcnt vmcnt(0)" ::: "memory");
        __builtin_amdgcn_sched_barrier(0);
      }
    }

    // ---- 6. unpack (v_perm, r8-proven) + h-part MFMAs ----
#pragma unroll
    for (int q = 0; q < 8; ++q) {
      i32x4 hp;
      hp[0] = (int)__builtin_amdgcn_perm((unsigned)hraw[2*q][1],   (unsigned)hraw[2*q][0],   0x05040100u);
      hp[1] = (int)__builtin_amdgcn_perm((unsigned)hraw[2*q][3],   (unsigned)hraw[2*q][2],   0x05040100u);
      hp[2] = (int)__builtin_amdgcn_perm((unsigned)hraw[2*q+1][1], (unsigned)hraw[2*q+1][0], 0x05040100u);
      hp[3] = (int)__builtin_amdgcn_perm((unsigned)hraw[2*q+1][3], (unsigned)hraw[2*q+1][2], 0x05040100u);
      s16x8 ah = __builtin_bit_cast(s16x8, hp);
      acc0 = __builtin_amdgcn_mfma_f32_16x16x32_bf16(ah, bfr[0][8 + q], acc0, 0, 0, 0);
      acc1 = __builtin_amdgcn_mfma_f32_16x16x32_bf16(ah, bfr[1][8 + q], acc1, 0, 0, 0);
    }

    // ---- 7. cross-wave epilogue (r3); B1 = lgkm-drain + raw barrier (NO vm drain) ----
#pragma unroll
    for (int rr = 0; rr < 4; ++rr) {
      elds[(grp * 4 + rr) * 132 + (wv * 2 + 0) * 16 + l15] = acc0[rr];
      elds[(grp * 4 + rr) * 132 + (wv * 2 + 1) * 16 + l15] = acc1[rr];
    }
    asm volatile("s_waitcnt lgkmcnt(0)" ::: "memory");
    __builtin_amdgcn_sched_barrier(0);
    __builtin_amdgcn_s_barrier();                       // B1
    __builtin_amdgcn_sched_barrier(0);

    const float* ez = &elds[erow * 132 + ntl * 16];
    float h0, h1;
    {
      float zf = ez[0 + jjl] + bia[0][0], zi = ez[4 + jjl] + bia[1][0];
      float zg = ez[8 + jjl] + bia[2][0], zo = ez[12 + jjl] + bia[3][0];
      float cn = sigf(zf) * cs0 + sigf(zi) * tanhfast(zg);
      h0 = sigf(zo) * tanhfast(cn); cs0 = cn; h0s = h0;
    }
    {
      float zf = ez[1 + jjl] + bia[0][1], zi = ez[5 + jjl] + bia[1][1];
      float zg = ez[9 + jjl] + bia[2][1], zo = ez[13 + jjl] + bia[3][1];
      float cn = sigf(zf) * cs1 + sigf(zi) * tanhfast(zg);
      h1 = sigf(zo) * tanhfast(cn); cs1 = cn; h1s = h1;
    }

    // ---- 8. tagged h(t+1) store (one dwordx2/thread); B2; hint flag (NO ack) ----
    const int rowg = r0 + erow;
    {
      const unsigned ttw = (unsigned)(t + 1) << 16;
      u32x2 hp2;
      hp2[0] = (unsigned)(unsigned short)f2bf(h0) | ttw;
      hp2[1] = (unsigned)(unsigned short)f2bf(h1) | ttw;
      st8t_cc(htag + (size_t)((t + 1) & 1) * (BATCH * DH)
              + (size_t)rowg * DH + csl * 32 + 2 * j2, hp2);
    }
    __builtin_amdgcn_sched_barrier(0);
    __builtin_amdgcn_s_barrier();                       // B2: all waves ISSUED stores
    __builtin_amdgcn_sched_barrier(0);
    if (tid == 0) st4_cc(myflag, (unsigned)(t + 1));

    // ---- 9. shadow: out store (fp32), x(t+2) prefetch ----
    {
      f32x2 ov; ov[0] = h0; ov[1] = h1;
      st8_p(out + ((size_t)t * BATCH + rowg) * DH + csl * 32 + 2 * j2, ov);
    }
    {
      const int tp = (t + 2 < T_STEPS) ? t + 2 : T_STEPS - 1;
      const float* xs = X + ((size_t)tp * BATCH + r0 + xrow) * DIN + xseg * 16;
      xp0 = *(const f32x4*)xs;       xp1 = *(const f32x4*)(xs + 4);
      xp2 = *(const f32x4*)(xs + 8); xp3 = *(const f32x4*)(xs + 12);
    }
  }

  // ---- final hx, cx (fp32, from registers; buffers in d_ws -> no aliasing) ----
  {
    const size_t base = (size_t)T_STEPS * BATCH * DH;
    const size_t idx  = (size_t)(r0 + erow) * DH + csl * 32 + 2 * j2;
    out[base + idx]     = h0s;
    out[base + idx + 1] = h1s;
    out[base + BATCH * DH + idx]     = cs0;
    out[base + BATCH * DH + idx + 1] = cs1;
  }
}

// =============== FALLBACK: round-10 kernel (proven correct; buffers fit in d_out tail) ===============
__global__ __launch_bounds__(NTHREADS, 1)
void lstm_v10_fb(const float* __restrict__ X,
                 const float* __restrict__ Wf, const float* __restrict__ bfv,
                 const float* __restrict__ Wi, const float* __restrict__ biv,
                 const float* __restrict__ Wg, const float* __restrict__ bgv,
                 const float* __restrict__ Wo, const float* __restrict__ bov,
                 float* __restrict__ out,
                 unsigned short* __restrict__ hbuf,
                 unsigned int* __restrict__ flags)
{
  const int bid = blockIdx.x;
  const int g   = bid & 7;
  const int csl = bid >> 3;
  const int tid = threadIdx.x;
  const int lane = tid & 63, wv = tid >> 6;
  const int grp = lane >> 4, l15 = lane & 15;
  const int r0 = g * 16;

  __shared__ short a_lds[2 * 32 * 16 * 8];
  __shared__ float elds[4 * 16 * 36];

  s16x8 bfr[2][16];
  {
    const float* Wm[4] = {Wf, Wi, Wg, Wo};
    const int gate = l15 >> 2, jj = l15 & 3;
    const float* Wsrc = Wm[gate];
#pragma unroll
    for (int n2 = 0; n2 < 2; ++n2) {
      const int hc = csl * 32 + (wv * 2 + n2) * 4 + jj;
#pragma unroll
      for (int kk = 0; kk < 16; ++kk) {
        const float* p = Wsrc + (size_t)(kk * 32 + grp * 8) * DH + hc;
        s16x8 f;
#pragma unroll
        for (int s = 0; s < 8; ++s) f[s] = f2bf(p[(size_t)s * DH]);
        bfr[n2][kk] = f;
      }
    }
  }
  const int colg = csl * 32 + wv * 8 + 2 * grp;
  float bia[4][2];
  {
    const float* Bv[4] = {bfv, biv, bgv, bov};
#pragma unroll
    for (int q = 0; q < 4; ++q) { bia[q][0] = Bv[q][colg]; bia[q][1] = Bv[q][colg + 1]; }
  }
  const int xrow = tid & 15, xseg = tid >> 4;
  f32x4 xp0, xp1, xp2, xp3;
  {
    const float* xs = X + (size_t)(r0 + xrow) * DIN + xseg * 16;
    s16x8 lo = cvt8(*(const f32x4*)xs, *(const f32x4*)(xs + 4));
    s16x8 hi = cvt8(*(const f32x4*)(xs + 8), *(const f32x4*)(xs + 12));
    *(s16x8*)&a_lds[((2 * xseg + 0) * 16 + xrow) * 8] = lo;
    *(s16x8*)&a_lds[((2 * xseg + 1) * 16 + xrow) * 8] = hi;
    const float* xn = X + ((size_t)1 * BATCH + r0 + xrow) * DIN + xseg * 16;
    xp0 = *(const f32x4*)xn;       xp1 = *(const f32x4*)(xn + 4);
    xp2 = *(const f32x4*)(xn + 8); xp3 = *(const f32x4*)(xn + 12);
  }
  __syncthreads();

  unsigned* myflag = flags + (g * 32 + csl * 4 + wv);
  const unsigned* pollp = flags + (g * 32 + (lane & 31));
  float* eldsw = &elds[wv * 16 * 36];
  float cs0 = 0.f, cs1 = 0.f, h0s = 0.f, h1s = 0.f;

  for (int t = 0; t < T_STEPS; ++t) {
    while (1) {
      unsigned v = ld4_cc(pollp);
      if (__all((int)(v >= (unsigned)t))) break;
    }
    __builtin_amdgcn_sched_barrier(0);
    const unsigned short* hr = hbuf + (size_t)(t & 1) * (BATCH * DH)
                             + (size_t)(r0 + l15) * DH + grp * 8;
    i32x4 hraw[8];
#pragma unroll
    for (int q = 0; q < 8; ++q) hraw[q] = ld16_cc(hr + q * 32);
    {
      short* ab = a_lds + ((t + 1) & 1) * (32 * 16 * 8);
      s16x8 lo = cvt8(xp0, xp1), hi = cvt8(xp2, xp3);
      *(s16x8*)&ab[((2 * xseg + 0) * 16 + xrow) * 8] = lo;
      *(s16x8*)&ab[((2 * xseg + 1) * 16 + xrow) * 8] = hi;
    }
    const short* ar = a_lds + (t & 1) * (32 * 16 * 8);
    f32x4 acc0 = {0.f,0.f,0.f,0.f}, acc1 = {0.f,0.f,0.f,0.f};
#pragma unroll
    for (int kk = 0; kk < 8; ++kk) {
      s16x8 a = *(const s16x8*)&ar[((kk * 4 + grp) * 16 + l15) * 8];
      acc0 = __builtin_amdgcn_mfma_f32_16x16x32_bf16(a, bfr[0][kk], acc0, 0, 0, 0);
      acc1 = __builtin_amdgcn_mfma_f32_16x16x32_bf16(a, bfr[1][kk], acc1, 0, 0, 0);
    }
    asm volatile("s_waitcnt vmcnt(0)" ::: "memory");
    __builtin_amdgcn_sched_barrier(0);
#pragma unroll
    for (int q = 0; q < 8; ++q) {
      s16x8 ah = __builtin_bit_cast(s16x8, hraw[q]);
      acc0 = __builtin_amdgcn_mfma_f32_16x16x32_bf16(ah, bfr[0][8 + q], acc0, 0, 0, 0);
      acc1 = __builtin_amdgcn_mfma_f32_16x16x32_bf16(ah, bfr[1][8 + q], acc1, 0, 0, 0);
    }
#pragma unroll
    for (int rr = 0; rr < 4; ++rr) {
      eldsw[(grp * 4 + rr) * 36 + l15]      = acc0[rr];
      eldsw[(grp * 4 + rr) * 36 + 16 + l15] = acc1[rr];
    }
    asm volatile("s_waitcnt lgkmcnt(0)" ::: "memory");
    __builtin_amdgcn_sched_barrier(0);
    float z0[4], z1[4];
    const int hc0 = 2 * grp, hc1 = 2 * grp + 1;
#pragma unroll
    for (int q = 0; q < 4; ++q) {
      z0[q] = eldsw[l15 * 36 + ((hc0 >> 2) << 4) + 4 * q + (hc0 & 3)];
      z1[q] = eldsw[l15 * 36 + ((hc1 >> 2) << 4) + 4 * q + (hc1 & 3)];
    }
    {
      float zf = z0[0] + bia[0][0], zi = z0[1] + bia[1][0];
      float zg = z0[2] + bia[2][0], zo = z0[3] + bia[3][0];
      cs0 = sigf(zf) * cs0 + sigf(zi) * tanhfast(zg);
      h0s = sigf(zo) * tanhfast(cs0);
    }
    {
      float zf = z1[0] + bia[0][1], zi = z1[1] + bia[1][1];
      float zg = z1[2] + bia[2][1], zo = z1[3] + bia[3][1];
      cs1 = sigf(zf) * cs1 + sigf(zi) * tanhfast(zg);
      h1s = sigf(zo) * tanhfast(cs1);
    }
    const int row = r0 + l15;
    {
      unsigned hpk = (unsigned)(unsigned short)f2bf(h0s)
                   | ((unsigned)(unsigned short)f2bf(h1s) << 16);
      st4_cc(hbuf + (size_t)((t + 1) & 1) * (BATCH * DH)
             + (size_t)row * DH + colg, hpk);
      f32x2 ov; ov[0] = h0s; ov[1] = h1s;
      st8_p(out + ((size_t)t * BATCH + row) * DH + colg, ov);
    }
    asm volatile("s_waitcnt vmcnt(1)" ::: "memory");
    if (lane == 0) st4_cc(myflag, (unsigned)(t + 1));
    {
      const int tp = (t + 2 < T_STEPS) ? t + 2 : T_STEPS - 1;
      const float* xs = X + ((size_t)tp * BATCH + r0 + xrow) * DIN + xseg * 16;
      xp0 = *(const f32x4*)xs;       xp1 = *(const f32x4*)(xs + 4);
      xp2 = *(const f32x4*)(xs + 8); xp3 = *(const f32x4*)(xs + 12);
    }
  }
  {
    const unsigned* fp = flags + tid;
    while (ld4_cc(fp) < (unsigned)T_STEPS) __builtin_amdgcn_s_sleep(1);
    __syncthreads();
  }
  {
    const size_t base = (size_t)T_STEPS * BATCH * DH;
    const size_t idx  = (size_t)(r0 + l15) * DH + colg;
    out[base + idx]     = h0s;
    out[base + idx + 1] = h1s;
    out[base + BATCH * DH + idx]     = cs0;
    out[base + BATCH * DH + idx + 1] = cs1;
  }
}

extern "C" void kernel_launch(void* const* d_in, const int* in_sizes, int n_in,
                              void* d_out, int out_size, void* d_ws, size_t ws_size,
                              hipStream_t stream) {
  const float* X   = (const float*)d_in[0];
  const float* Wf  = (const float*)d_in[1];
  const float* bf_ = (const float*)d_in[2];
  const float* Wi  = (const float*)d_in[3];
  const float* bi_ = (const float*)d_in[4];
  const float* Wg  = (const float*)d_in[5];
  const float* bg_ = (const float*)d_in[6];
  const float* Wo  = (const float*)d_in[7];
  const float* bo_ = (const float*)d_in[8];
  float* out = (float*)d_out;

  const size_t tagbytes = (size_t)2 * BATCH * DH * 4;   // 262144
  const size_t fbytes   = 1024;
  if (ws_size >= tagbytes + fbytes) {
    unsigned* htag  = (unsigned*)d_ws;
    unsigned* flags = (unsigned*)((unsigned char*)d_ws + tagbytes);
    hipMemsetAsync(d_ws, 0, tagbytes + fbytes, stream);  // tag0 == t=0, h=0
    lstm_v11<<<NWG, NTHREADS, 0, stream>>>(X, Wf, bf_, Wi, bi_, Wg, bg_,
                                           Wo, bo_, out, htag, flags);
    return;
  }
  // fallback: untagged r10 engine, buffers in d_out tail (fits: 128K+1K < 256K)
  unsigned char* tail = (unsigned char*)d_out + (size_t)T_STEPS * BATCH * DH * 4;
  unsigned short* hbuf = (unsigned short*)tail;
  unsigned int* flags  = (unsigned int*)(tail + 131072);
  hipMemsetAsync(tail, 0, 131072 + 1024, stream);
  lstm_v10_fb<<<NWG, NTHREADS, 0, stream>>>(X, Wf, bf_, Wi, bi_, Wg, bg_,
                                            Wo, bo_, out, hbuf, flags);
}